// Round 10
// baseline (59.870 us; speedup 1.0000x reference)
//
#include <hip/hip_runtime.h>
#include <math.h>

// LazyEqProp closed form (verified rounds 1-9):
//   E  = x @ We^T + be
//   m0 = mean|E|  > eps ;  H0 = m0 * 0.5*tanh(E  @ W0^T + b0)
//   m1 = mean|H0| > eps ;  H1 = m1 * 0.5*tanh(H0 @ W1^T + b1)
//   m2 = mean|H1| > eps ;  H2 = m2 * 0.5*tanh(H1 @ W2^T + b2)
//   out = H2 @ Wh^T + bh
//
// Round 10: round-6 skeleton (6 dispatches; r9's convert-split was neutral,
// r5/r7 proved in-kernel cross-block sync is a loss). Change: BK=128.
//  - 8 K-steps instead of 16: halves barrier+waitcnt stall rounds
//  - staging/fragment math for BK=128 proven correct in round 8
//  - 8 waves kept (2/SIMD mandatory per round 8), wave tile 32x32
//  - triple buffer 3 x 48 KB = 144 KB (<=160 KB; grid 256 = 1 block/CU
//    anyway, so occupancy unchanged), counted vmcnt(6), depth-2 prefetch

using half_t = _Float16;
typedef _Float16 f16x4 __attribute__((ext_vector_type(4)));
typedef _Float16 f16x8 __attribute__((ext_vector_type(8)));
typedef float    f32x4 __attribute__((ext_vector_type(4)));

constexpr int KDIM = 1024;
constexpr int ROWB = KDIM * 2;   // bytes per swizzled f16 row
constexpr int BUFB = 49152;      // LDS per buffer: P 32 KB + Q 16 KB
constexpr float EPS_GATE = 0.01f;

__device__ __forceinline__ float tanh_fast(float z) {
    return 1.0f - 2.0f / (__expf(2.0f * z) + 1.0f);  // safe at +-inf
}

__device__ __forceinline__ void gload16(const void* g, void* l) {
    __builtin_amdgcn_global_load_lds(
        (const __attribute__((address_space(1))) void*)g,
        (__attribute__((address_space(3))) void*)l, 16, 0, 0);
}

// ---- fp32 -> swizzled fp16 (row r, byte p holds element (p ^ ((r&7)<<4))/2)
//      + zero the 3 row-sum accumulators (blocks 0..5)
__global__ __launch_bounds__(256)
void convert_all(const float* __restrict__ x,  const float* __restrict__ We,
                 const float* __restrict__ W,  const float* __restrict__ Wh,
                 half_t* __restrict__ x16, half_t* __restrict__ We16,
                 half_t* __restrict__ W16, half_t* __restrict__ Wh16,
                 float* __restrict__ msum) {
    const int bid = blockIdx.x;
    const int t = threadIdx.x;
    if (bid < 6) ((f32x4*)msum)[bid * 256 + t] = f32x4{0.f, 0.f, 0.f, 0.f};
    const float* src; half_t* dst; int row;
    if (bid < 2048)      { src = x;  dst = x16;  row = bid; }
    else if (bid < 3072) { src = We; dst = We16; row = bid - 2048; }
    else if (bid < 6144) { src = W;  dst = W16;  row = bid - 3072; }
    else                 { src = Wh; dst = Wh16; row = bid - 6144; }
    const f32x4 v = *(const f32x4*)(src + (size_t)row * KDIM + 4 * t);
    f16x4 h;
    h[0] = (half_t)v[0]; h[1] = (half_t)v[1]; h[2] = (half_t)v[2]; h[3] = (half_t)v[3];
    const int p = (8 * t) ^ ((row & 7) << 4);
    *(f16x4*)((char*)dst + (size_t)row * ROWB + p) = h;
}

// ---- NT gemm: O[m,n] = epi( sum_k P[m,k]*Q[n,k] + bias[n] )
// P,Q swizzled f16. Block tile 128m x 64n x 128k; 8 waves (4m x 2n), wave
// tile 32x32. Triple-buffered LDS, counted vmcnt(6), setprio around MFMA.
// EPI: 0 = bias -> swz f16; 1 = mask(msum_in)*0.5*tanh(.+bias) -> swz f16;
//      2 = bias -> f32.  EMIT: atomicAdd per-row |out| partials.
template <int EPI, bool EMIT>
__global__ __launch_bounds__(512)
void gemm8w(const half_t* __restrict__ P, const half_t* __restrict__ Q,
            const float* __restrict__ bias, const float* __restrict__ msum_in,
            float* __restrict__ msum_out, void* __restrict__ Out, int Nout) {
    // 3 buffers x (P 32 KB | Q 16 KB) = 144 KB (LDS 160 KB; grid=256 -> 1/CU)
    __shared__ alignas(16) char smem[3 * BUFB];

    const int tid = threadIdx.x;
    const int bid = blockIdx.x;
    // XCD-aware: xcd = bid&7 owns m-tiles {2x,2x+1} across all n-tiles.
    const int m0 = ((bid & 7) * 2 + ((bid >> 3) & 1)) * 128;
    const int n0 = (bid >> 4) * 64;

    // staging per K-step (256 B/row slab, swizzle is local to 128-B halves so
    // a linear copy of bytes [s*256, s*256+256) preserves the read math):
    // P = 2048 granules (4/thread), Q = 1024 (2/thread); 6 loads/thread.
    const char* gsP[4]; int ldP[4];
#pragma unroll
    for (int i = 0; i < 4; ++i) {
        const int G = tid + 512 * i;
        gsP[i] = (const char*)P + (size_t)(m0 + (G >> 4)) * ROWB + (G & 15) * 16;
        ldP[i] = G * 16;
    }
    const char* gsQ[2]; int ldQ[2];
#pragma unroll
    for (int c = 0; c < 2; ++c) {
        const int g = tid + 512 * c;
        gsQ[c] = (const char*)Q + (size_t)(n0 + (g >> 4)) * ROWB + (g & 15) * 16;
        ldQ[c] = 32768 + g * 16;
    }

    const int lane = tid & 63;
    const int w = tid >> 6;            // 8 waves: 4m x 2n, wave tile 32x32
    const int wm = (w & 3) * 32;
    const int wn = (w >> 2) * 32;
    const int l15 = lane & 15, l4 = lane >> 4;
    const int pxor = (lane & 7) << 4;

    f32x4 acc[2][2] = {};  // [n-frag][m-frag]

    auto stage = [&](int s) {
        const int go = s * 256;
        char* base = smem + (s % 3) * BUFB;
#pragma unroll
        for (int i = 0; i < 4; ++i) gload16(gsP[i] + go, base + ldP[i]);
#pragma unroll
        for (int c = 0; c < 2; ++c) gload16(gsQ[c] + go, base + ldQ[c]);
    };

    stage(0);
    stage(1);

    for (int s = 0; s < 8; ++s) {
        // own DMAs for tile s done; tile s+1's 6 stay in flight (in-order
        // vmcnt completion keeps this safe even with stray earlier loads).
        if (s == 7) asm volatile("s_waitcnt vmcnt(0)" ::: "memory");
        else        asm volatile("s_waitcnt vmcnt(6)" ::: "memory");
        __builtin_amdgcn_s_barrier();   // all waves' tile-s DMAs landed
        asm volatile("" ::: "memory");
        if (s < 6) stage(s + 2);        // overwrites buf((s-1)%3): reads done
        const char* PtB = smem + (s % 3) * BUFB;
        const char* QtB = PtB + 32768;
        __builtin_amdgcn_s_setprio(1);
#pragma unroll
        for (int h = 0; h < 4; ++h) {   // 4 k-halves of 32
            const int ko = ((h >> 1) * 128) + ((((h & 1) * 64) + l4 * 16) ^ pxor);
            f16x8 qa[2], pb[2];
#pragma unroll
            for (int i = 0; i < 2; ++i)
                qa[i] = *(const f16x8*)(QtB + (wn + i * 16 + l15) * 256 + ko);
#pragma unroll
            for (int j = 0; j < 2; ++j)
                pb[j] = *(const f16x8*)(PtB + (wm + j * 16 + l15) * 256 + ko);
#pragma unroll
            for (int i = 0; i < 2; ++i)
#pragma unroll
                for (int j = 0; j < 2; ++j)
                    acc[i][j] = __builtin_amdgcn_mfma_f32_16x16x32_f16(qa[i], pb[j], acc[i][j], 0, 0, 0);
        }
        __builtin_amdgcn_s_setprio(0);
    }

    // ---- epilogue: lane holds m = m0+wm+j*16+l15, n = n0+wn+i*16+l4*4+e
#pragma unroll
    for (int j = 0; j < 2; ++j) {
        const int m = m0 + wm + j * 16 + l15;
        float msk = 1.0f;
        if (EPI == 1) msk = (msum_in[m] * (1.0f / 1024.0f) > EPS_GATE) ? 1.0f : 0.0f;
        float rsum = 0.0f;
#pragma unroll
        for (int i = 0; i < 2; ++i) {
            const int n = n0 + wn + i * 16 + l4 * 4;
            const f32x4 bz = *(const f32x4*)(bias + n);
            float v[4];
#pragma unroll
            for (int e = 0; e < 4; ++e) {
                v[e] = acc[i][j][e] + bz[e];
                if (EPI == 1) v[e] = msk * (0.5f * tanh_fast(v[e]));
                if (EMIT) rsum += fabsf(v[e]);
            }
            if (EPI == 2) {
                f32x4 o; o[0] = v[0]; o[1] = v[1]; o[2] = v[2]; o[3] = v[3];
                *(f32x4*)((float*)Out + (size_t)m * Nout + n) = o;
            } else {
                f16x4 hv;
                hv[0] = (half_t)v[0]; hv[1] = (half_t)v[1];
                hv[2] = (half_t)v[2]; hv[3] = (half_t)v[3];
                const int p = (n * 2) ^ ((m & 7) << 4);
                *(f16x4*)((char*)Out + (size_t)m * ROWB + p) = hv;
            }
        }
        if (EMIT) {  // reduce over the 4 l4-lanes sharing this row, one atomic
            rsum += __shfl_xor(rsum, 16, 64);
            rsum += __shfl_xor(rsum, 32, 64);
            if (l4 == 0) atomicAdd(msum_out + m, rsum);
        }
    }
}

extern "C" void kernel_launch(void* const* d_in, const int* in_sizes, int n_in,
                              void* d_out, int out_size, void* d_ws, size_t ws_size,
                              hipStream_t stream) {
    const float* x  = (const float*)d_in[0];  // [2048,1024]
    const float* We = (const float*)d_in[1];  // [1024,1024]
    const float* be = (const float*)d_in[2];  // [1024]
    const float* W  = (const float*)d_in[3];  // [3,1024,1024]
    const float* b  = (const float*)d_in[4];  // [3,1024]
    const float* Wh = (const float*)d_in[5];  // [512,1024]
    const float* bh = (const float*)d_in[6];  // [512]

    const int B = 2048, H = 1024, O = 512;

    half_t* s0   = (half_t*)d_ws;                   // x16 / H0 / H2
    half_t* s1   = s0 + (size_t)B * H;              // E / H1
    half_t* We16 = s1 + (size_t)B * H;
    half_t* W16  = We16 + (size_t)H * H;
    half_t* Wh16 = W16 + (size_t)3 * H * H;
    float*  msum = (float*)(Wh16 + (size_t)O * H);  // 3 x 2048 f32
    float*  out  = (float*)d_out;

    convert_all<<<6656, 256, 0, stream>>>(x, We, W, Wh, s0, We16, W16, Wh16, msum);

    // E = x @ We^T + be; emit |E| row sums -> msum0
    gemm8w<0, true ><<<256, 512, 0, stream>>>(s0, We16, be, nullptr, msum, s1, H);
    // H0 = m0 * 0.5*tanh(E @ W0^T + b0); emit -> msum1
    gemm8w<1, true ><<<256, 512, 0, stream>>>(s1, W16, b, msum, msum + 2048, s0, H);
    // H1; emit -> msum2
    gemm8w<1, true ><<<256, 512, 0, stream>>>(s0, W16 + (size_t)H * H, b + H,
                                              msum + 2048, msum + 4096, s1, H);
    // H2 (no emit)
    gemm8w<1, false><<<256, 512, 0, stream>>>(s1, W16 + (size_t)2 * H * H, b + 2 * H,
                                              msum + 4096, nullptr, s0, H);
    // head -> f32 out
    gemm8w<2, false><<<128, 512, 0, stream>>>(s0, Wh16, bh, nullptr, nullptr, out, O);
}

// Round 11
// 55.966 us; speedup vs baseline: 1.0698x; 1.0698x over previous
//
#include <hip/hip_runtime.h>
#include <math.h>

// LazyEqProp closed form (verified rounds 1-10):
//   E  = x @ We^T + be
//   m0 = mean|E|  > eps ;  H0 = m0 * 0.5*tanh(E  @ W0^T + b0)
//   m1 = mean|H0| > eps ;  H1 = m1 * 0.5*tanh(H0 @ W1^T + b1)
//   m2 = mean|H1| > eps ;  H2 = m2 * 0.5*tanh(H1 @ W2^T + b2)
//   out = H2 @ Wh^T + bh
//
// Round 11: attack the 1-block/CU lockstep. 64x64 tiles -> grid 512 ->
// 2 independent blocks/CU (4 waves each, same 2 waves/SIMD density as r6,
// but barrier stalls of one block overlap the other block's compute).
// Intra-block schedule identical to round 6: BK=64, triple buffer,
// counted vmcnt(4), depth-2 prefetch, setprio, swizzled-f16 layout,
// global_load_lds width-16, fused mask epilogue + atomicAdd row sums.

using half_t = _Float16;
typedef _Float16 f16x4 __attribute__((ext_vector_type(4)));
typedef _Float16 f16x8 __attribute__((ext_vector_type(8)));
typedef float    f32x4 __attribute__((ext_vector_type(4)));

constexpr int KDIM = 1024;
constexpr int ROWB = KDIM * 2;   // bytes per swizzled f16 row
constexpr int BUFB = 16384;      // LDS per buffer: P 8 KB + Q 8 KB
constexpr float EPS_GATE = 0.01f;

__device__ __forceinline__ float tanh_fast(float z) {
    return 1.0f - 2.0f / (__expf(2.0f * z) + 1.0f);  // safe at +-inf
}

__device__ __forceinline__ void gload16(const void* g, void* l) {
    __builtin_amdgcn_global_load_lds(
        (const __attribute__((address_space(1))) void*)g,
        (__attribute__((address_space(3))) void*)l, 16, 0, 0);
}

// ---- fp32 -> swizzled fp16 (row r, byte p holds element (p ^ ((r&7)<<4))/2)
//      + zero the 3 row-sum accumulators (blocks 0..5)
__global__ __launch_bounds__(256)
void convert_all(const float* __restrict__ x,  const float* __restrict__ We,
                 const float* __restrict__ W,  const float* __restrict__ Wh,
                 half_t* __restrict__ x16, half_t* __restrict__ We16,
                 half_t* __restrict__ W16, half_t* __restrict__ Wh16,
                 float* __restrict__ msum) {
    const int bid = blockIdx.x;
    const int t = threadIdx.x;
    if (bid < 6) ((f32x4*)msum)[bid * 256 + t] = f32x4{0.f, 0.f, 0.f, 0.f};
    const float* src; half_t* dst; int row;
    if (bid < 2048)      { src = x;  dst = x16;  row = bid; }
    else if (bid < 3072) { src = We; dst = We16; row = bid - 2048; }
    else if (bid < 6144) { src = W;  dst = W16;  row = bid - 3072; }
    else                 { src = Wh; dst = Wh16; row = bid - 6144; }
    const f32x4 v = *(const f32x4*)(src + (size_t)row * KDIM + 4 * t);
    f16x4 h;
    h[0] = (half_t)v[0]; h[1] = (half_t)v[1]; h[2] = (half_t)v[2]; h[3] = (half_t)v[3];
    const int p = (8 * t) ^ ((row & 7) << 4);
    *(f16x4*)((char*)dst + (size_t)row * ROWB + p) = h;
}

// ---- NT gemm: O[m,n] = epi( sum_k P[m,k]*Q[n,k] + bias[n] )
// P,Q swizzled f16. Block tile 64m x 64n x 64k; 4 waves (2m x 2n), wave tile
// 32x32; 256 threads; 48 KB LDS -> 2 blocks/CU co-resident.
// EPI: 0 = bias -> swz f16; 1 = mask(msum_in)*0.5*tanh(.+bias) -> swz f16;
//      2 = bias -> f32.  EMIT: atomicAdd per-row |out| partials.
template <int EPI, bool EMIT>
__global__ __launch_bounds__(256)
void gemm2b(const half_t* __restrict__ P, const half_t* __restrict__ Q,
            const float* __restrict__ bias, const float* __restrict__ msum_in,
            float* __restrict__ msum_out, void* __restrict__ Out, int Nout) {
    __shared__ alignas(16) char smem[3 * BUFB];  // 48 KB

    const int tid = threadIdx.x;
    const int bid = blockIdx.x;
    // XCD-bijective map (grid 512 or 256, both %8==0): xcd = bid&7 owns
    // m-panels {4x..4x+3}; 32 m-tiles x (Nout/64) n-tiles.
    const int m0 = ((bid & 7) * 4 + ((bid >> 3) & 3)) * 64;
    const int n0 = (bid >> 5) * 64;

    // staging: P 512 granules (2/thread), Q 512 (2/thread); linear LDS dest
    const char* gsP[2]; int ldP[2];
#pragma unroll
    for (int i = 0; i < 2; ++i) {
        const int G = tid + 256 * i;
        gsP[i] = (const char*)P + (size_t)(m0 + (G >> 3)) * ROWB + (G & 7) * 16;
        ldP[i] = G * 16;
    }
    const char* gsQ[2]; int ldQ[2];
#pragma unroll
    for (int c = 0; c < 2; ++c) {
        const int g = tid + 256 * c;
        gsQ[c] = (const char*)Q + (size_t)(n0 + (g >> 3)) * ROWB + (g & 7) * 16;
        ldQ[c] = 8192 + g * 16;
    }

    const int lane = tid & 63;
    const int w = tid >> 6;           // 4 waves: 2m x 2n, wave tile 32x32
    const int wm = (w & 1) * 32;
    const int wn = (w >> 1) * 32;
    const int l15 = lane & 15, l4 = lane >> 4;
    const int off0 = (l4 * 16) ^ ((lane & 7) << 4);
    const int off1 = off0 ^ 64;

    f32x4 acc[2][2] = {};  // [n-frag][m-frag]

    auto stage = [&](int s) {
        const int go = s * 128;
        char* base = smem + (s % 3) * BUFB;
#pragma unroll
        for (int i = 0; i < 2; ++i) gload16(gsP[i] + go, base + ldP[i]);
#pragma unroll
        for (int c = 0; c < 2; ++c) gload16(gsQ[c] + go, base + ldQ[c]);
    };

    stage(0);
    stage(1);

    for (int s = 0; s < 16; ++s) {
        // own DMAs for tile s done; tile s+1's 4 stay in flight.
        if (s == 15) asm volatile("s_waitcnt vmcnt(0)" ::: "memory");
        else         asm volatile("s_waitcnt vmcnt(4)" ::: "memory");
        __builtin_amdgcn_s_barrier();   // all waves' tile-s DMAs landed
        asm volatile("" ::: "memory");
        if (s < 14) stage(s + 2);       // overwrites buf((s-1)%3): reads done
        const char* PtB = smem + (s % 3) * BUFB;
        const char* QtB = PtB + 8192;
        __builtin_amdgcn_s_setprio(1);
#pragma unroll
        for (int h = 0; h < 2; ++h) {
            const int ko = h ? off1 : off0;
            f16x8 qa[2], pb[2];
#pragma unroll
            for (int i = 0; i < 2; ++i)
                qa[i] = *(const f16x8*)(QtB + (wn + i * 16 + l15) * 128 + ko);
#pragma unroll
            for (int j = 0; j < 2; ++j)
                pb[j] = *(const f16x8*)(PtB + (wm + j * 16 + l15) * 128 + ko);
#pragma unroll
            for (int i = 0; i < 2; ++i)
#pragma unroll
                for (int j = 0; j < 2; ++j)
                    acc[i][j] = __builtin_amdgcn_mfma_f32_16x16x32_f16(qa[i], pb[j], acc[i][j], 0, 0, 0);
        }
        __builtin_amdgcn_s_setprio(0);
    }

    // ---- epilogue: lane holds m = m0+wm+j*16+l15, n = n0+wn+i*16+l4*4+e
#pragma unroll
    for (int j = 0; j < 2; ++j) {
        const int m = m0 + wm + j * 16 + l15;
        float msk = 1.0f;
        if (EPI == 1) msk = (msum_in[m] * (1.0f / 1024.0f) > EPS_GATE) ? 1.0f : 0.0f;
        float rsum = 0.0f;
#pragma unroll
        for (int i = 0; i < 2; ++i) {
            const int n = n0 + wn + i * 16 + l4 * 4;
            const f32x4 bz = *(const f32x4*)(bias + n);
            float v[4];
#pragma unroll
            for (int e = 0; e < 4; ++e) {
                v[e] = acc[i][j][e] + bz[e];
                if (EPI == 1) v[e] = msk * (0.5f * tanh_fast(v[e]));
                if (EMIT) rsum += fabsf(v[e]);
            }
            if (EPI == 2) {
                f32x4 o; o[0] = v[0]; o[1] = v[1]; o[2] = v[2]; o[3] = v[3];
                *(f32x4*)((float*)Out + (size_t)m * Nout + n) = o;
            } else {
                f16x4 hv;
                hv[0] = (half_t)v[0]; hv[1] = (half_t)v[1];
                hv[2] = (half_t)v[2]; hv[3] = (half_t)v[3];
                const int p = (n * 2) ^ ((m & 7) << 4);
                *(f16x4*)((char*)Out + (size_t)m * ROWB + p) = hv;
            }
        }
        if (EMIT) {  // reduce over the 4 l4-lanes sharing this row, one atomic
            rsum += __shfl_xor(rsum, 16, 64);
            rsum += __shfl_xor(rsum, 32, 64);
            if (l4 == 0) atomicAdd(msum_out + m, rsum);
        }
    }
}

extern "C" void kernel_launch(void* const* d_in, const int* in_sizes, int n_in,
                              void* d_out, int out_size, void* d_ws, size_t ws_size,
                              hipStream_t stream) {
    const float* x  = (const float*)d_in[0];  // [2048,1024]
    const float* We = (const float*)d_in[1];  // [1024,1024]
    const float* be = (const float*)d_in[2];  // [1024]
    const float* W  = (const float*)d_in[3];  // [3,1024,1024]
    const float* b  = (const float*)d_in[4];  // [3,1024]
    const float* Wh = (const float*)d_in[5];  // [512,1024]
    const float* bh = (const float*)d_in[6];  // [512]

    const int B = 2048, H = 1024, O = 512;

    half_t* s0   = (half_t*)d_ws;                   // x16 / H0 / H2
    half_t* s1   = s0 + (size_t)B * H;              // E / H1
    half_t* We16 = s1 + (size_t)B * H;
    half_t* W16  = We16 + (size_t)H * H;
    half_t* Wh16 = W16 + (size_t)3 * H * H;
    float*  msum = (float*)(Wh16 + (size_t)O * H);  // 3 x 2048 f32
    float*  out  = (float*)d_out;

    convert_all<<<6656, 256, 0, stream>>>(x, We, W, Wh, s0, We16, W16, Wh16, msum);

    // E = x @ We^T + be; emit |E| row sums -> msum0
    gemm2b<0, true ><<<512, 256, 0, stream>>>(s0, We16, be, nullptr, msum, s1, H);
    // H0 = m0 * 0.5*tanh(E @ W0^T + b0); emit -> msum1
    gemm2b<1, true ><<<512, 256, 0, stream>>>(s1, W16, b, msum, msum + 2048, s0, H);
    // H1; emit -> msum2
    gemm2b<1, true ><<<512, 256, 0, stream>>>(s0, W16 + (size_t)H * H, b + H,
                                              msum + 2048, msum + 4096, s1, H);
    // H2 (no emit)
    gemm2b<1, false><<<512, 256, 0, stream>>>(s1, W16 + (size_t)2 * H * H, b + 2 * H,
                                              msum + 4096, nullptr, s0, H);
    // head -> f32 out (32 m-tiles x 8 n-tiles = 256 blocks)
    gemm2b<2, false><<<256, 256, 0, stream>>>(s0, Wh16, bh, nullptr, nullptr, out, O);
}